// Round 1
// baseline (147.835 us; speedup 1.0000x reference)
//
#include <hip/hip_runtime.h>

// Problem constants (fixed by the reference):
//   input:       [TP=8, NTOK=2048, HIDDEN=8192] f32
//   residual:    [NTOK, HIDDEN] f32
//   norm_weight: [HIDDEN] f32
// Outputs (concatenated in d_out): output [NTOK,HIDDEN], residual_out [NTOK,HIDDEN]
constexpr int TP     = 8;
constexpr int HIDDEN = 8192;
constexpr int BLOCK  = 256;
constexpr int VPT    = HIDDEN / (BLOCK * 4);  // 8 float4 per thread
constexpr float EPS  = 1e-6f;

__global__ __launch_bounds__(BLOCK) void ar_residual_rmsnorm_kernel(
    const float* __restrict__ in,         // [TP, ntok, HIDDEN]
    const float* __restrict__ resid,      // [ntok, HIDDEN]
    const float* __restrict__ w,          // [HIDDEN]
    float* __restrict__ out,              // [ntok, HIDDEN]
    float* __restrict__ resid_out,        // [ntok, HIDDEN]
    int ntok)
{
    const int row = blockIdx.x;
    const int tid = threadIdx.x;
    const size_t row_off     = (size_t)row * HIDDEN;
    const size_t rank_stride = (size_t)ntok * HIDDEN;

    // Pass 1: allreduce-sum + residual add, keep result in registers,
    // store residual_out, accumulate sum of squares.
    float4 v[VPT];
    float ss = 0.f;
    #pragma unroll
    for (int p = 0; p < VPT; ++p) {
        const int col = (tid + p * BLOCK) * 4;  // float index, 16B aligned
        float4 acc = *(const float4*)(resid + row_off + col);
        #pragma unroll
        for (int r = 0; r < TP; ++r) {
            float4 x = *(const float4*)(in + (size_t)r * rank_stride + row_off + col);
            acc.x += x.x; acc.y += x.y; acc.z += x.z; acc.w += x.w;
        }
        v[p] = acc;
        *(float4*)(resid_out + row_off + col) = acc;
        ss += acc.x * acc.x + acc.y * acc.y + acc.z * acc.z + acc.w * acc.w;
    }

    // Block reduction of ss: butterfly within each 64-lane wave, then LDS.
    #pragma unroll
    for (int o = 32; o > 0; o >>= 1) ss += __shfl_down(ss, o, 64);
    __shared__ float s_ss[BLOCK / 64];
    const int wid = tid >> 6;
    if ((tid & 63) == 0) s_ss[wid] = ss;
    __syncthreads();
    float tot = 0.f;
    #pragma unroll
    for (int i = 0; i < BLOCK / 64; ++i) tot += s_ss[i];

    const float inv = rsqrtf(tot * (1.0f / HIDDEN) + EPS);

    // Pass 2: normalize from registers, apply weight, store output.
    #pragma unroll
    for (int p = 0; p < VPT; ++p) {
        const int col = (tid + p * BLOCK) * 4;
        float4 wv = *(const float4*)(w + col);
        float4 o4;
        o4.x = v[p].x * inv * wv.x;
        o4.y = v[p].y * inv * wv.y;
        o4.z = v[p].z * inv * wv.z;
        o4.w = v[p].w * inv * wv.w;
        *(float4*)(out + row_off + col) = o4;
    }
}

extern "C" void kernel_launch(void* const* d_in, const int* in_sizes, int n_in,
                              void* d_out, int out_size, void* d_ws, size_t ws_size,
                              hipStream_t stream) {
    const float* in    = (const float*)d_in[0];
    const float* resid = (const float*)d_in[1];
    const float* w     = (const float*)d_in[2];

    const int hidden = in_sizes[2];          // 8192
    const int ntok   = in_sizes[1] / hidden; // 2048

    float* out       = (float*)d_out;                        // [ntok, hidden]
    float* resid_out = (float*)d_out + (size_t)ntok * hidden; // [ntok, hidden]

    ar_residual_rmsnorm_kernel<<<ntok, BLOCK, 0, stream>>>(
        in, resid, w, out, resid_out, ntok);
}

// Round 2
// 128.688 us; speedup vs baseline: 1.1488x; 1.1488x over previous
//
#include <hip/hip_runtime.h>

// Problem constants (fixed by the reference):
//   input:       [TP=8, NTOK=2048, HIDDEN=8192] f32
//   residual:    [NTOK, HIDDEN] f32
//   norm_weight: [HIDDEN] f32
// Outputs (concatenated in d_out): output [NTOK,HIDDEN], residual_out [NTOK,HIDDEN]
constexpr int TP     = 8;
constexpr int HIDDEN = 8192;
constexpr int BLOCK  = 256;
constexpr int VPT    = HIDDEN / (BLOCK * 4);  // 8 float4 per thread
constexpr float EPS  = 1e-6f;

typedef float f32x4 __attribute__((ext_vector_type(4)));

__global__ __launch_bounds__(BLOCK) void ar_residual_rmsnorm_kernel(
    const float* __restrict__ in,         // [TP, ntok, HIDDEN]
    const float* __restrict__ resid,      // [ntok, HIDDEN]
    const float* __restrict__ w,          // [HIDDEN]
    float* __restrict__ out,              // [ntok, HIDDEN]
    float* __restrict__ resid_out,        // [ntok, HIDDEN]
    int ntok)
{
    const int row = blockIdx.x;
    const int tid = threadIdx.x;
    const size_t row_off     = (size_t)row * HIDDEN;
    const size_t rank_stride = (size_t)ntok * HIDDEN;

    // Pass 1: allreduce-sum + residual add, keep result in registers,
    // store residual_out (non-temporal), accumulate sum of squares.
    f32x4 v[VPT];
    float ss = 0.f;
    #pragma unroll
    for (int p = 0; p < VPT; ++p) {
        const int col = (tid + p * BLOCK) * 4;  // float index, 16B aligned
        const float* base = in + row_off + col;
        // 8 independent streaming loads, pairwise tree sum.
        f32x4 x0 = __builtin_nontemporal_load((const f32x4*)(base + 0 * rank_stride));
        f32x4 x1 = __builtin_nontemporal_load((const f32x4*)(base + 1 * rank_stride));
        f32x4 x2 = __builtin_nontemporal_load((const f32x4*)(base + 2 * rank_stride));
        f32x4 x3 = __builtin_nontemporal_load((const f32x4*)(base + 3 * rank_stride));
        f32x4 x4 = __builtin_nontemporal_load((const f32x4*)(base + 4 * rank_stride));
        f32x4 x5 = __builtin_nontemporal_load((const f32x4*)(base + 5 * rank_stride));
        f32x4 x6 = __builtin_nontemporal_load((const f32x4*)(base + 6 * rank_stride));
        f32x4 x7 = __builtin_nontemporal_load((const f32x4*)(base + 7 * rank_stride));
        f32x4 rv = __builtin_nontemporal_load((const f32x4*)(resid + row_off + col));
        f32x4 s01 = x0 + x1, s23 = x2 + x3, s45 = x4 + x5, s67 = x6 + x7;
        f32x4 acc = (s01 + s23) + (s45 + s67) + rv;
        v[p] = acc;
        __builtin_nontemporal_store(acc, (f32x4*)(resid_out + row_off + col));
        ss += acc.x * acc.x + acc.y * acc.y + acc.z * acc.z + acc.w * acc.w;
    }

    // Block reduction of ss: butterfly within each 64-lane wave, then LDS.
    #pragma unroll
    for (int o = 32; o > 0; o >>= 1) ss += __shfl_down(ss, o, 64);
    __shared__ float s_ss[BLOCK / 64];
    const int wid = tid >> 6;
    if ((tid & 63) == 0) s_ss[wid] = ss;
    __syncthreads();
    float tot = 0.f;
    #pragma unroll
    for (int i = 0; i < BLOCK / 64; ++i) tot += s_ss[i];

    const float inv = rsqrtf(tot * (1.0f / HIDDEN) + EPS);

    // Pass 2: normalize from registers, apply weight (cached load), store output.
    #pragma unroll
    for (int p = 0; p < VPT; ++p) {
        const int col = (tid + p * BLOCK) * 4;
        f32x4 wv = *(const f32x4*)(w + col);   // reused by all blocks -> keep cached
        f32x4 o4 = v[p] * inv * wv;
        __builtin_nontemporal_store(o4, (f32x4*)(out + row_off + col));
    }
}

extern "C" void kernel_launch(void* const* d_in, const int* in_sizes, int n_in,
                              void* d_out, int out_size, void* d_ws, size_t ws_size,
                              hipStream_t stream) {
    const float* in    = (const float*)d_in[0];
    const float* resid = (const float*)d_in[1];
    const float* w     = (const float*)d_in[2];

    const int hidden = in_sizes[2];          // 8192
    const int ntok   = in_sizes[1] / hidden; // 2048

    float* out       = (float*)d_out;                         // [ntok, hidden]
    float* resid_out = (float*)d_out + (size_t)ntok * hidden; // [ntok, hidden]

    ar_residual_rmsnorm_kernel<<<ntok, BLOCK, 0, stream>>>(
        in, resid, w, out, resid_out, ntok);
}